// Round 5
// baseline (204.584 us; speedup 1.0000x reference)
//
#include <hip/hip_runtime.h>
#include <math.h>

#define POS_WEIGHT 7.0f
#define POSITION_WEIGHT 0.1f
#define BLOCK 256
#define STEP 2048              // rows per block-step (256 threads x 8 rows)
#define STEPS 4                // steps per block
#define RPB (STEP * STEPS)     // rows per block = 8192

// p = sigmoid(d), stable, fast hw ops only
__device__ __forceinline__ float sigp(float d) {
    float e  = __expf(-fabsf(d));
    float rt = __builtin_amdgcn_rcpf(1.0f + e);
    return (d >= 0.0f ? 1.0f : e) * rt;
}

// weighted NLL from p: nll = -log(label ? p : 1-p), w = label ? 7 : 1
__device__ __forceinline__ void acc_nll(int la, float p, float& s_wnll, float& s_w) {
    float sel = la ? p : 1.0f - p;
    float w   = la ? POS_WEIGHT : 1.0f;
    s_wnll = fmaf(w, -__logf(sel), s_wnll);
    s_w += w;
}

__device__ __forceinline__ void pair_term(int la0, int ba0, float p0,
                                          int la1, int ba1, float p1, float& s_pos) {
    if (ba0 == ba1 && (la0 | la1)) s_pos += fabsf(p1 - p0);
}

struct StepRegs {
    float4 L0, L1, L2, L3;
    int4 laA, laB, baA, baB;
};

__device__ __forceinline__ void load_step(StepRegs& r, const float* logits,
                                          const int* labels, const int* batch,
                                          int row0, int t) {
    const float4* lg4 = (const float4*)logits + (row0 >> 1);
    const int4*   lb4 = (const int4*)labels + (row0 >> 2);
    const int4*   bt4 = (const int4*)batch  + (row0 >> 2);
    r.L0 = lg4[t]; r.L1 = lg4[256 + t]; r.L2 = lg4[512 + t]; r.L3 = lg4[768 + t];
    r.laA = lb4[t]; r.laB = lb4[256 + t];
    r.baA = bt4[t]; r.baB = bt4[256 + t];
}

__global__ __launch_bounds__(BLOCK, 4) void pos_loss_kernel(
    const float* __restrict__ logits,   // [n,2]
    const int*   __restrict__ labels,   // [n]
    const int*   __restrict__ batch,    // [n]
    float* __restrict__ acc,            // [4]: wnll, w, pos, counter(int)
    float* __restrict__ out,
    int n)
{
    __shared__ __align__(16) float Pf[STEP + 8];   // p per row of this step (+pad)
    __shared__ int   Mb[2 * BLOCK];                // first-meta of each thread's groups
    __shared__ float prevP;                        // carry across steps/blocks
    __shared__ int   prevM;

    const int t  = threadIdx.x;
    const long long bb = (long long)blockIdx.x * RPB;

    float s_wnll = 0.f, s_w = 0.f, s_pos = 0.f;
    float carry_p = 0.f; int carry_m = -2;         // ba = -1 sentinel, never matches

    // block-boundary predecessor (row bb-1), once per block, one thread
    if (t == BLOCK - 1 && bb > 0 && bb < n) {
        int i = (int)bb - 1;
        float2 lp = ((const float2*)logits)[i];
        carry_p = sigp(lp.y - lp.x);
        carry_m = (batch[i] << 1) | labels[i];
    }

    StepRegs cur, nxt;
    if (bb + STEP <= n)
        load_step(cur, logits, labels, batch, (int)bb, t);   // prologue prefetch

    #pragma unroll
    for (int s = 0; s < STEPS; ++s) {
        const long long row0l = bb + (long long)s * STEP;
        if (row0l >= n) break;
        const int row0 = (int)row0l;

        if (row0 + STEP <= n) {
            // ---------- fast full step; data already in cur ----------
            if (t == BLOCK - 1) { prevP = carry_p; prevM = carry_m; }

            // phase A: p in the coalesced domain -> LDS (label-free)
            float2* P2 = (float2*)Pf;
            P2[t]       = make_float2(sigp(cur.L0.y - cur.L0.x), sigp(cur.L0.w - cur.L0.z));
            P2[256 + t] = make_float2(sigp(cur.L1.y - cur.L1.x), sigp(cur.L1.w - cur.L1.z));
            P2[512 + t] = make_float2(sigp(cur.L2.y - cur.L2.x), sigp(cur.L2.w - cur.L2.z));
            P2[768 + t] = make_float2(sigp(cur.L3.y - cur.L3.x), sigp(cur.L3.w - cur.L3.z));
            Mb[t]         = (cur.baA.x << 1) | cur.laA.x;
            Mb[BLOCK + t] = (cur.baB.x << 1) | cur.laB.x;
            __syncthreads();

            // prefetch next step (registers only) — overlaps phase B compute
            const bool havenext = (s + 1 < STEPS) && (row0 + 2 * STEP <= n);
            if (havenext)
                load_step(nxt, logits, labels, batch, row0 + STEP, t);

            // phase B: row-aligned consumption (4 contiguous rows x 2 groups)
            float4 pA = ((const float4*)Pf)[t];          // rows 4t..4t+3
            float4 pB = ((const float4*)Pf)[256 + t];    // rows 1024+4t..+3
            float pA4 = Pf[4 * t + 4];                   // row 4t+4
            float pB4 = Pf[1024 + 4 * t + 4];            // row 1024+4t+4 (t=255 guarded)

            acc_nll(cur.laA.x, pA.x, s_wnll, s_w);
            acc_nll(cur.laA.y, pA.y, s_wnll, s_w);
            acc_nll(cur.laA.z, pA.z, s_wnll, s_w);
            acc_nll(cur.laA.w, pA.w, s_wnll, s_w);
            acc_nll(cur.laB.x, pB.x, s_wnll, s_w);
            acc_nll(cur.laB.y, pB.y, s_wnll, s_w);
            acc_nll(cur.laB.z, pB.z, s_wnll, s_w);
            acc_nll(cur.laB.w, pB.w, s_wnll, s_w);

            pair_term(cur.laA.x, cur.baA.x, pA.x, cur.laA.y, cur.baA.y, pA.y, s_pos);
            pair_term(cur.laA.y, cur.baA.y, pA.y, cur.laA.z, cur.baA.z, pA.z, s_pos);
            pair_term(cur.laA.z, cur.baA.z, pA.z, cur.laA.w, cur.baA.w, pA.w, s_pos);
            { int m = Mb[t + 1]; pair_term(cur.laA.w, cur.baA.w, pA.w, m & 1, m >> 1, pA4, s_pos); }
            pair_term(cur.laB.x, cur.baB.x, pB.x, cur.laB.y, cur.baB.y, pB.y, s_pos);
            pair_term(cur.laB.y, cur.baB.y, pB.y, cur.laB.z, cur.baB.z, pB.z, s_pos);
            pair_term(cur.laB.z, cur.baB.z, pB.z, cur.laB.w, cur.baB.w, pB.w, s_pos);
            if (t < BLOCK - 1) {
                int m = Mb[BLOCK + t + 1];
                pair_term(cur.laB.w, cur.baB.w, pB.w, m & 1, m >> 1, pB4, s_pos);
            }
            if (t == 0)
                pair_term(prevM & 1, prevM >> 1, prevP, cur.laA.x, cur.baA.x, pA.x, s_pos);
            if (t == BLOCK - 1) { carry_p = pB.w; carry_m = (cur.baB.w << 1) | cur.laB.w; }
            __syncthreads();
            if (havenext) cur = nxt;
        } else {
            // ---------- masked tail step (never hit for N=16M) ----------
            if (t == BLOCK - 1) { prevP = carry_p; prevM = carry_m; }
            __syncthreads();
            for (int g = 0; g < 2; ++g) {
                int rb = row0 + g * 1024 + 4 * t;
                #pragma unroll
                for (int k = 0; k < 4; ++k) {
                    int r = rb + k;
                    if (r < n) {
                        float2 lp = ((const float2*)logits)[r];
                        int la = labels[r], ba = batch[r];
                        float p = sigp(lp.y - lp.x);
                        acc_nll(la, p, s_wnll, s_w);
                        if (r + 1 < n) {
                            float2 lq = ((const float2*)logits)[r + 1];
                            pair_term(la, ba, p, labels[r + 1], batch[r + 1],
                                      sigp(lq.y - lq.x), s_pos);
                        }
                    }
                }
            }
            if (t == 0) {
                float2 lp = ((const float2*)logits)[row0];
                pair_term(prevM & 1, prevM >> 1, prevP,
                          labels[row0], batch[row0], sigp(lp.y - lp.x), s_pos);
            }
            __syncthreads();
        }
    }

    // wave(64) reduce -> block partial
    #pragma unroll
    for (int off = 32; off > 0; off >>= 1) {
        s_wnll += __shfl_down(s_wnll, off);
        s_w    += __shfl_down(s_w, off);
        s_pos  += __shfl_down(s_pos, off);
    }
    __shared__ float sa[BLOCK / 64], sb[BLOCK / 64], sc[BLOCK / 64];
    int lane = t & 63, wid = t >> 6;
    if (lane == 0) { sa[wid] = s_wnll; sb[wid] = s_w; sc[wid] = s_pos; }
    __syncthreads();

    // fused finalize: 3 atomics per block + last-block-done writes out
    if (t == 0) {
        float ta = 0.f, tb = 0.f, tc = 0.f;
        #pragma unroll
        for (int w = 0; w < BLOCK / 64; ++w) { ta += sa[w]; tb += sb[w]; tc += sc[w]; }
        atomicAdd(&acc[0], ta);
        atomicAdd(&acc[1], tb);
        atomicAdd(&acc[2], tc);
        __threadfence();
        int prev = atomicAdd((int*)&acc[3], 1);
        if (prev == (int)gridDim.x - 1) {
            float A = atomicAdd(&acc[0], 0.f);   // coherent reads
            float B = atomicAdd(&acc[1], 0.f);
            float C = atomicAdd(&acc[2], 0.f);
            out[0] = A / B + POSITION_WEIGHT * C;
        }
    }
}

extern "C" void kernel_launch(void* const* d_in, const int* in_sizes, int n_in,
                              void* d_out, int out_size, void* d_ws, size_t ws_size,
                              hipStream_t stream) {
    const float* logits = (const float*)d_in[0];
    const int*   labels = (const int*)d_in[1];
    const int*   batch  = (const int*)d_in[2];
    float* out = (float*)d_out;
    float* acc = (float*)d_ws;
    int n = in_sizes[1];   // labels element count == N

    int nblocks = (n + RPB - 1) / RPB;   // 2048 for N=16M
    hipMemsetAsync(acc, 0, 4 * sizeof(float), stream);
    pos_loss_kernel<<<nblocks, BLOCK, 0, stream>>>(logits, labels, batch, acc, out, n);
}

// Round 6
// 53.631 us; speedup vs baseline: 3.8147x; 3.8147x over previous
//
#include <hip/hip_runtime.h>
#include <math.h>

#define POS_WEIGHT 7.0f
#define POSITION_WEIGHT 0.1f
#define BLOCK 256
#define STEP 2048              // rows per block (256 threads x 8 rows) — one shot

// p = sigmoid(d), stable, fast hw ops only
__device__ __forceinline__ float sigp(float d) {
    float e  = __expf(-fabsf(d));
    float rt = __builtin_amdgcn_rcpf(1.0f + e);
    return (d >= 0.0f ? 1.0f : e) * rt;
}

// weighted NLL from p: nll = -log(label ? p : 1-p), w = label ? 7 : 1
__device__ __forceinline__ void acc_nll(int la, float p, float& s_wnll, float& s_w) {
    float sel = la ? p : 1.0f - p;
    float w   = la ? POS_WEIGHT : 1.0f;
    s_wnll = fmaf(w, -__logf(sel), s_wnll);
    s_w += w;
}

__device__ __forceinline__ void pair_term(int la0, int ba0, float p0,
                                          int la1, int ba1, float p1, float& s_pos) {
    if (ba0 == ba1 && (la0 | la1)) s_pos += fabsf(p1 - p0);
}

__global__ __launch_bounds__(BLOCK) void pos_loss_kernel(
    const float* __restrict__ logits,   // [n,2]
    const int*   __restrict__ labels,   // [n]
    const int*   __restrict__ batch,    // [n]
    float4* __restrict__ partials,      // [nblocks]
    int n)
{
    __shared__ __align__(16) float Pf[STEP + 8];   // p per row of this block (+pad)
    __shared__ int   Mb[2 * BLOCK];                // first-meta of each thread's groups
    __shared__ float prevP;                        // block-boundary carry
    __shared__ int   prevM;

    const int t    = threadIdx.x;
    const int row0 = blockIdx.x * STEP;

    float s_wnll = 0.f, s_w = 0.f, s_pos = 0.f;

    if (row0 + STEP <= n) {
        // ---------- fast full block: all loads lane-stride-16B coalesced ----------
        const float4* lg4 = (const float4*)logits + (row0 >> 1);
        const int4*   lb4 = (const int4*)labels + (row0 >> 2);
        const int4*   bt4 = (const int4*)batch  + (row0 >> 2);

        float4 L0 = lg4[t];           // rows 2t, 2t+1
        float4 L1 = lg4[256 + t];     // rows 512+2t, +1
        float4 L2 = lg4[512 + t];     // rows 1024+2t, +1
        float4 L3 = lg4[768 + t];     // rows 1536+2t, +1
        int4 laA = lb4[t];            // rows 4t..4t+3
        int4 laB = lb4[256 + t];      // rows 1024+4t..+3
        int4 baA = bt4[t];
        int4 baB = bt4[256 + t];

        // block-boundary predecessor (row row0-1), one thread
        if (t == BLOCK - 1) {
            if (row0 > 0) {
                int i = row0 - 1;
                float2 lp = ((const float2*)logits)[i];
                prevP = sigp(lp.y - lp.x);
                prevM = (batch[i] << 1) | labels[i];
            } else {
                prevP = 0.f; prevM = -2;          // never matches
            }
        }

        // phase A: p in the coalesced domain -> LDS (label-free)
        float2* P2 = (float2*)Pf;
        P2[t]       = make_float2(sigp(L0.y - L0.x), sigp(L0.w - L0.z));
        P2[256 + t] = make_float2(sigp(L1.y - L1.x), sigp(L1.w - L1.z));
        P2[512 + t] = make_float2(sigp(L2.y - L2.x), sigp(L2.w - L2.z));
        P2[768 + t] = make_float2(sigp(L3.y - L3.x), sigp(L3.w - L3.z));
        Mb[t]         = (baA.x << 1) | laA.x;
        Mb[BLOCK + t] = (baB.x << 1) | laB.x;
        __syncthreads();

        // phase B: row-aligned consumption (4 contiguous rows x 2 groups)
        float4 pA = ((const float4*)Pf)[t];          // rows 4t..4t+3
        float4 pB = ((const float4*)Pf)[256 + t];    // rows 1024+4t..+3
        float pA4 = Pf[4 * t + 4];                   // row 4t+4 (t=255 -> row 1024, valid)
        float pB4 = Pf[1024 + 4 * t + 4];            // row 1024+4t+4 (t=255 -> pad, guarded)

        acc_nll(laA.x, pA.x, s_wnll, s_w);
        acc_nll(laA.y, pA.y, s_wnll, s_w);
        acc_nll(laA.z, pA.z, s_wnll, s_w);
        acc_nll(laA.w, pA.w, s_wnll, s_w);
        acc_nll(laB.x, pB.x, s_wnll, s_w);
        acc_nll(laB.y, pB.y, s_wnll, s_w);
        acc_nll(laB.z, pB.z, s_wnll, s_w);
        acc_nll(laB.w, pB.w, s_wnll, s_w);

        pair_term(laA.x, baA.x, pA.x, laA.y, baA.y, pA.y, s_pos);
        pair_term(laA.y, baA.y, pA.y, laA.z, baA.z, pA.z, s_pos);
        pair_term(laA.z, baA.z, pA.z, laA.w, baA.w, pA.w, s_pos);
        { int m = Mb[t + 1]; pair_term(laA.w, baA.w, pA.w, m & 1, m >> 1, pA4, s_pos); }
        pair_term(laB.x, baB.x, pB.x, laB.y, baB.y, pB.y, s_pos);
        pair_term(laB.y, baB.y, pB.y, laB.z, baB.z, pB.z, s_pos);
        pair_term(laB.z, baB.z, pB.z, laB.w, baB.w, pB.w, s_pos);
        if (t < BLOCK - 1) {
            int m = Mb[BLOCK + t + 1];
            pair_term(laB.w, baB.w, pB.w, m & 1, m >> 1, pB4, s_pos);
        }
        if (t == 0)
            pair_term(prevM & 1, prevM >> 1, prevP, laA.x, baA.x, pA.x, s_pos);
    } else if (row0 < n) {
        // ---------- masked tail block (never hit for N=16M) ----------
        if (t == BLOCK - 1) {
            if (row0 > 0) {
                int i = row0 - 1;
                float2 lp = ((const float2*)logits)[i];
                prevP = sigp(lp.y - lp.x);
                prevM = (batch[i] << 1) | labels[i];
            } else {
                prevP = 0.f; prevM = -2;
            }
        }
        __syncthreads();
        for (int g = 0; g < 2; ++g) {
            int rb = row0 + g * 1024 + 4 * t;
            #pragma unroll
            for (int k = 0; k < 4; ++k) {
                int r = rb + k;
                if (r < n) {
                    float2 lp = ((const float2*)logits)[r];
                    int la = labels[r], ba = batch[r];
                    float p = sigp(lp.y - lp.x);
                    acc_nll(la, p, s_wnll, s_w);
                    if (r + 1 < n) {
                        float2 lq = ((const float2*)logits)[r + 1];
                        pair_term(la, ba, p, labels[r + 1], batch[r + 1],
                                  sigp(lq.y - lq.x), s_pos);
                    }
                }
            }
        }
        if (t == 0) {
            float2 lp = ((const float2*)logits)[row0];
            pair_term(prevM & 1, prevM >> 1, prevP,
                      labels[row0], batch[row0], sigp(lp.y - lp.x), s_pos);
        }
    }

    // wave(64) reduce -> block partial
    #pragma unroll
    for (int off = 32; off > 0; off >>= 1) {
        s_wnll += __shfl_down(s_wnll, off);
        s_w    += __shfl_down(s_w, off);
        s_pos  += __shfl_down(s_pos, off);
    }
    __shared__ float sa[BLOCK / 64], sb[BLOCK / 64], sc[BLOCK / 64];
    int lane = t & 63, wid = t >> 6;
    if (lane == 0) { sa[wid] = s_wnll; sb[wid] = s_w; sc[wid] = s_pos; }
    __syncthreads();
    if (t == 0) {
        float ta = 0.f, tb = 0.f, tc = 0.f;
        #pragma unroll
        for (int w = 0; w < BLOCK / 64; ++w) { ta += sa[w]; tb += sb[w]; tc += sc[w]; }
        partials[blockIdx.x] = make_float4(ta, tb, tc, 0.f);
    }
}

__global__ __launch_bounds__(256) void finalize_kernel(
    const float4* __restrict__ partials, int nb, float* __restrict__ out)
{
    float a = 0.f, b = 0.f, c = 0.f;
    for (int i = threadIdx.x; i < nb; i += 256) {
        float4 v = partials[i];
        a += v.x; b += v.y; c += v.z;
    }
    #pragma unroll
    for (int off = 32; off > 0; off >>= 1) {
        a += __shfl_down(a, off);
        b += __shfl_down(b, off);
        c += __shfl_down(c, off);
    }
    __shared__ float sa[4], sb[4], sc[4];
    int lane = threadIdx.x & 63, wid = threadIdx.x >> 6;
    if (lane == 0) { sa[wid] = a; sb[wid] = b; sc[wid] = c; }
    __syncthreads();
    if (threadIdx.x == 0) {
        float ta = 0.f, tb = 0.f, tc = 0.f;
        #pragma unroll
        for (int w = 0; w < 4; ++w) { ta += sa[w]; tb += sb[w]; tc += sc[w]; }
        out[0] = ta / tb + POSITION_WEIGHT * tc;
    }
}

extern "C" void kernel_launch(void* const* d_in, const int* in_sizes, int n_in,
                              void* d_out, int out_size, void* d_ws, size_t ws_size,
                              hipStream_t stream) {
    const float* logits = (const float*)d_in[0];
    const int*   labels = (const int*)d_in[1];
    const int*   batch  = (const int*)d_in[2];
    float* out = (float*)d_out;
    float4* partials = (float4*)d_ws;
    int n = in_sizes[1];   // labels element count == N

    int nblocks = (n + STEP - 1) / STEP;   // 8192 for N=16M
    pos_loss_kernel<<<nblocks, BLOCK, 0, stream>>>(logits, labels, batch, partials, n);
    finalize_kernel<<<1, 256, 0, stream>>>(partials, nblocks, out);
}

// Round 7
// 48.258 us; speedup vs baseline: 4.2394x; 1.1113x over previous
//
#include <hip/hip_runtime.h>
#include <math.h>

#define POS_WEIGHT 7.0f
#define POSITION_WEIGHT 0.1f
#define BLOCK 512
#define STEP 2048              // rows per step (512 threads x 4 rows)
#define STEPS 4
#define RPB (STEP * STEPS)     // 8192 rows per block

// p = sigmoid(d), stable, fast hw ops only
__device__ __forceinline__ float sigp(float d) {
    float e  = __expf(-fabsf(d));
    float rt = __builtin_amdgcn_rcpf(1.0f + e);
    return (d >= 0.0f ? 1.0f : e) * rt;
}

// weighted NLL from p: nll = -log(label ? p : 1-p), w = label ? 7 : 1
__device__ __forceinline__ void acc_nll(int la, float p, float& s_wnll, float& s_w) {
    float sel = la ? p : 1.0f - p;
    float w   = la ? POS_WEIGHT : 1.0f;
    s_wnll = fmaf(w, -__logf(sel), s_wnll);
    s_w += w;
}

__device__ __forceinline__ void pair_term(int la0, int ba0, float p0,
                                          int la1, int ba1, float p1, float& s_pos) {
    if (ba0 == ba1 && (la0 | la1)) s_pos += fabsf(p1 - p0);
}

// Two named register banks (a/b); no arrays, no conditional copies -> no scratch.
// Thread t owns rows 4t..4t+3 of each step (int4 meta domain); logits come as
// two float4 (rows 2t,2t+1 and 1024+2t,1024+2t+1) in the coalesced domain.
#define DECLB(BK) float4 L0##BK, L1##BK; int4 lA##BK, bA##BK

#define LOADB(BK, S) do { \
    const float4* lg4_ = (const float4*)logits + ((row0 + (S) * STEP) >> 1); \
    const int4*   lb4_ = (const int4*)labels  + ((row0 + (S) * STEP) >> 2); \
    const int4*   bt4_ = (const int4*)batch   + ((row0 + (S) * STEP) >> 2); \
    L0##BK = lg4_[t]; L1##BK = lg4_[BLOCK + t]; \
    lA##BK = lb4_[t]; bA##BK = bt4_[t]; \
} while (0)

// phase A: sigp in the coalesced domain -> LDS; first-row meta -> Mb;
// t==BLOCK-1 publishes the carry (last row of this step) for step S+1.
#define PHASEA(BK, S) do { \
    if ((S) + 1 < STEPS && t == BLOCK - 1) { \
        cP[(S) + 1] = sigp(L1##BK.w - L1##BK.z); \
        cM[(S) + 1] = (bA##BK.w << 1) | lA##BK.w; \
    } \
    float2* P2_ = (float2*)Pf; \
    P2_[t]         = make_float2(sigp(L0##BK.y - L0##BK.x), sigp(L0##BK.w - L0##BK.z)); \
    P2_[BLOCK + t] = make_float2(sigp(L1##BK.y - L1##BK.x), sigp(L1##BK.w - L1##BK.z)); \
    Mb[t] = (bA##BK.x << 1) | lA##BK.x; \
} while (0)

// phase B: row-aligned consumption of 4 contiguous rows per thread
#define PHASEB(BK, S) do { \
    float4 pA  = ((const float4*)Pf)[t]; \
    float  pA4 = Pf[4 * t + 4]; \
    acc_nll(lA##BK.x, pA.x, s_wnll, s_w); \
    acc_nll(lA##BK.y, pA.y, s_wnll, s_w); \
    acc_nll(lA##BK.z, pA.z, s_wnll, s_w); \
    acc_nll(lA##BK.w, pA.w, s_wnll, s_w); \
    pair_term(lA##BK.x, bA##BK.x, pA.x, lA##BK.y, bA##BK.y, pA.y, s_pos); \
    pair_term(lA##BK.y, bA##BK.y, pA.y, lA##BK.z, bA##BK.z, pA.z, s_pos); \
    pair_term(lA##BK.z, bA##BK.z, pA.z, lA##BK.w, bA##BK.w, pA.w, s_pos); \
    if (t < BLOCK - 1) { \
        int m_ = Mb[t + 1]; \
        pair_term(lA##BK.w, bA##BK.w, pA.w, m_ & 1, m_ >> 1, pA4, s_pos); \
    } \
    if (t == 0) \
        pair_term(cM[(S)] & 1, cM[(S)] >> 1, cP[(S)], lA##BK.x, bA##BK.x, pA.x, s_pos); \
} while (0)

__global__ __launch_bounds__(BLOCK, 8) void pos_loss_kernel(
    const float* __restrict__ logits,   // [n,2]
    const int*   __restrict__ labels,   // [n]
    const int*   __restrict__ batch,    // [n]
    float4* __restrict__ partials,      // [nblocks]
    int n)
{
    __shared__ __align__(16) float Pf[STEP + 8];   // p per row of current step (+pad)
    __shared__ int   Mb[BLOCK];                    // first-row meta per thread
    __shared__ float cP[STEPS];                    // carry p into step s
    __shared__ int   cM[STEPS];                    // carry meta into step s

    const int t    = threadIdx.x;
    const int row0 = blockIdx.x * RPB;

    float s_wnll = 0.f, s_w = 0.f, s_pos = 0.f;

    if (row0 + RPB <= n) {
        // ---------- fast full block: 4-step software pipeline ----------
        if (t == BLOCK - 1) {
            if (row0 > 0) {
                int i = row0 - 1;
                float2 lp = ((const float2*)logits)[i];
                cP[0] = sigp(lp.y - lp.x);
                cM[0] = (batch[i] << 1) | labels[i];
            } else { cP[0] = 0.f; cM[0] = -2; }     // sentinel: never matches
        }
        DECLB(a); DECLB(b);
        LOADB(a, 0);
        // step 0
        PHASEA(a, 0);
        LOADB(b, 1);                // prefetch: ~2 barriers + phase B to complete
        __syncthreads();
        PHASEB(a, 0);
        __syncthreads();
        // step 1
        PHASEA(b, 1);
        LOADB(a, 2);
        __syncthreads();
        PHASEB(b, 1);
        __syncthreads();
        // step 2
        PHASEA(a, 2);
        LOADB(b, 3);
        __syncthreads();
        PHASEB(a, 2);
        __syncthreads();
        // step 3
        PHASEA(b, 3);
        __syncthreads();
        PHASEB(b, 3);
    } else if (row0 < n) {
        // ---------- masked tail block (never hit when n % RPB == 0) ----------
        const int tb = row0 + t * (RPB / BLOCK);
        const int te = min(tb + RPB / BLOCK, n);
        if (tb < n) {
            float pp = 0.f; int pm = -2;
            if (tb > 0) {
                int i = tb - 1;
                float2 lp = ((const float2*)logits)[i];
                pp = sigp(lp.y - lp.x);
                pm = (batch[i] << 1) | labels[i];
            }
            for (int r = tb; r < te; ++r) {
                float2 lp = ((const float2*)logits)[r];
                float p = sigp(lp.y - lp.x);
                int la = labels[r], ba = batch[r];
                acc_nll(la, p, s_wnll, s_w);
                pair_term(pm & 1, pm >> 1, pp, la, ba, p, s_pos);
                pp = p; pm = (ba << 1) | la;
            }
        }
    }

    // wave(64) reduce -> block partial
    #pragma unroll
    for (int off = 32; off > 0; off >>= 1) {
        s_wnll += __shfl_down(s_wnll, off);
        s_w    += __shfl_down(s_w, off);
        s_pos  += __shfl_down(s_pos, off);
    }
    __shared__ float sa[BLOCK / 64], sb[BLOCK / 64], sc[BLOCK / 64];
    int lane = t & 63, wid = t >> 6;
    if (lane == 0) { sa[wid] = s_wnll; sb[wid] = s_w; sc[wid] = s_pos; }
    __syncthreads();
    if (t == 0) {
        float ta = 0.f, tb2 = 0.f, tc = 0.f;
        #pragma unroll
        for (int w = 0; w < BLOCK / 64; ++w) { ta += sa[w]; tb2 += sb[w]; tc += sc[w]; }
        partials[blockIdx.x] = make_float4(ta, tb2, tc, 0.f);
    }
}

__global__ __launch_bounds__(256) void finalize_kernel(
    const float4* __restrict__ partials, int nb, float* __restrict__ out)
{
    float a = 0.f, b = 0.f, c = 0.f;
    for (int i = threadIdx.x; i < nb; i += 256) {
        float4 v = partials[i];
        a += v.x; b += v.y; c += v.z;
    }
    #pragma unroll
    for (int off = 32; off > 0; off >>= 1) {
        a += __shfl_down(a, off);
        b += __shfl_down(b, off);
        c += __shfl_down(c, off);
    }
    __shared__ float sa[4], sb[4], sc[4];
    int lane = threadIdx.x & 63, wid = threadIdx.x >> 6;
    if (lane == 0) { sa[wid] = a; sb[wid] = b; sc[wid] = c; }
    __syncthreads();
    if (threadIdx.x == 0) {
        float ta = 0.f, tb = 0.f, tc = 0.f;
        #pragma unroll
        for (int w = 0; w < 4; ++w) { ta += sa[w]; tb += sb[w]; tc += sc[w]; }
        out[0] = ta / tb + POSITION_WEIGHT * tc;
    }
}

extern "C" void kernel_launch(void* const* d_in, const int* in_sizes, int n_in,
                              void* d_out, int out_size, void* d_ws, size_t ws_size,
                              hipStream_t stream) {
    const float* logits = (const float*)d_in[0];
    const int*   labels = (const int*)d_in[1];
    const int*   batch  = (const int*)d_in[2];
    float* out = (float*)d_out;
    float4* partials = (float4*)d_ws;
    int n = in_sizes[1];   // labels element count == N

    int nblocks = (n + RPB - 1) / RPB;   // 2048 for N=16M
    pos_loss_kernel<<<nblocks, BLOCK, 0, stream>>>(logits, labels, batch, partials, n);
    finalize_kernel<<<1, 256, 0, stream>>>(partials, nblocks, out);
}

// Round 8
// 48.111 us; speedup vs baseline: 4.2523x; 1.0030x over previous
//
#include <hip/hip_runtime.h>
#include <math.h>

#define POS_WEIGHT 7.0f
#define POSITION_WEIGHT 0.1f
#define BLOCK 256
#define UPT 16                 // units per thread (unit = 2 consecutive rows)

// p = sigmoid(d), stable, fast hw ops only
__device__ __forceinline__ float sigp(float d) {
    float e  = __expf(-fabsf(d));
    float rt = __builtin_amdgcn_rcpf(1.0f + e);
    return (d >= 0.0f ? 1.0f : e) * rt;
}

// weighted NLL from p: nll = -log(label ? p : 1-p), w = label ? 7 : 1
__device__ __forceinline__ void acc_nll(int la, float p, float& s_wnll, float& s_w) {
    float sel = la ? p : 1.0f - p;
    float w   = la ? POS_WEIGHT : 1.0f;
    s_wnll = fmaf(w, -__logf(sel), s_wnll);
    s_w += w;
}

__device__ __forceinline__ void pair_term(int la0, int ba0, float p0,
                                          int la1, int ba1, float p1, float& s_pos) {
    if (ba0 == ba1 && (la0 | la1)) s_pos += fabsf(p1 - p0);
}

__global__ __launch_bounds__(BLOCK, 4) void pos_loss_kernel(
    const float* __restrict__ logits,   // [n,2]
    const int*   __restrict__ labels,   // [n]
    const int*   __restrict__ batch,    // [n]
    float4* __restrict__ partials,      // [nblocks]
    int n)
{
    const int t    = threadIdx.x;
    const int lane = t & 63;
    const int NU   = n >> 1;                     // units of 2 rows
    const int upb  = BLOCK * UPT;                // units per block
    const int g0   = blockIdx.x * upb;

    float s_wnll = 0.f, s_w = 0.f, s_pos = 0.f;

    const float4* lg4 = (const float4*)logits;
    const int2*   lb2 = (const int2*)labels;
    const int2*   bt2 = (const int2*)batch;

    #pragma unroll 4
    for (int it = 0; it < UPT; ++it) {
        const int g = g0 + it * BLOCK + t;       // lane-contiguous units
        float p0 = 0.f, p1 = 0.f;
        int2 la = make_int2(0, 0), ba = make_int2(-3, -3);

        if (g < NU) {
            float4 L = lg4[g];                   // rows 2g, 2g+1
            la = lb2[g];
            ba = bt2[g];
            p0 = sigp(L.y - L.x);
            p1 = sigp(L.w - L.z);
            acc_nll(la.x, p0, s_wnll, s_w);
            acc_nll(la.y, p1, s_wnll, s_w);
            pair_term(la.x, ba.x, p0, la.y, ba.y, p1, s_pos);
        }

        // cross-unit pair (rows 2g+1, 2g+2): next lane's unit head
        float np0 = __shfl_down(p0, 1);
        int   nla = __shfl_down(la.x, 1);
        int   nba = __shfl_down(ba.x, 1);
        if (lane == 63 && g + 1 < NU) {          // wave boundary: direct fixup
            float2 lp = ((const float2*)logits)[2 * g + 2];
            np0 = sigp(lp.y - lp.x);
            nla = labels[2 * g + 2];
            nba = batch[2 * g + 2];
        }
        if (g + 1 < NU)
            pair_term(la.y, ba.y, p1, nla, nba, np0, s_pos);
    }

    // odd-n leftover row (never hit for N=16M)
    if ((n & 1) && blockIdx.x == 0 && t == 0) {
        int r = n - 1;
        float2 lp = ((const float2*)logits)[r];
        float p = sigp(lp.y - lp.x);
        int la1 = labels[r], ba1 = batch[r];
        acc_nll(la1, p, s_wnll, s_w);
        if (r > 0) {
            float2 lq = ((const float2*)logits)[r - 1];
            pair_term(labels[r - 1], batch[r - 1], sigp(lq.y - lq.x),
                      la1, ba1, p, s_pos);
        }
    }

    // wave(64) reduce -> block partial
    #pragma unroll
    for (int off = 32; off > 0; off >>= 1) {
        s_wnll += __shfl_down(s_wnll, off);
        s_w    += __shfl_down(s_w, off);
        s_pos  += __shfl_down(s_pos, off);
    }
    __shared__ float sa[BLOCK / 64], sb[BLOCK / 64], sc[BLOCK / 64];
    int wid = t >> 6;
    if (lane == 0) { sa[wid] = s_wnll; sb[wid] = s_w; sc[wid] = s_pos; }
    __syncthreads();
    if (t == 0) {
        float ta = 0.f, tb = 0.f, tc = 0.f;
        #pragma unroll
        for (int w = 0; w < BLOCK / 64; ++w) { ta += sa[w]; tb += sb[w]; tc += sc[w]; }
        partials[blockIdx.x] = make_float4(ta, tb, tc, 0.f);
    }
}

__global__ __launch_bounds__(256) void finalize_kernel(
    const float4* __restrict__ partials, int nb, float* __restrict__ out)
{
    float a = 0.f, b = 0.f, c = 0.f;
    for (int i = threadIdx.x; i < nb; i += 256) {
        float4 v = partials[i];
        a += v.x; b += v.y; c += v.z;
    }
    #pragma unroll
    for (int off = 32; off > 0; off >>= 1) {
        a += __shfl_down(a, off);
        b += __shfl_down(b, off);
        c += __shfl_down(c, off);
    }
    __shared__ float sa[4], sb[4], sc[4];
    int lane = threadIdx.x & 63, wid = threadIdx.x >> 6;
    if (lane == 0) { sa[wid] = a; sb[wid] = b; sc[wid] = c; }
    __syncthreads();
    if (threadIdx.x == 0) {
        float ta = 0.f, tb = 0.f, tc = 0.f;
        #pragma unroll
        for (int w = 0; w < 4; ++w) { ta += sa[w]; tb += sb[w]; tc += sc[w]; }
        out[0] = ta / tb + POSITION_WEIGHT * tc;
    }
}

extern "C" void kernel_launch(void* const* d_in, const int* in_sizes, int n_in,
                              void* d_out, int out_size, void* d_ws, size_t ws_size,
                              hipStream_t stream) {
    const float* logits = (const float*)d_in[0];
    const int*   labels = (const int*)d_in[1];
    const int*   batch  = (const int*)d_in[2];
    float* out = (float*)d_out;
    float4* partials = (float4*)d_ws;
    int n = in_sizes[1];   // labels element count == N

    int NU = n >> 1;
    int upb = BLOCK * UPT;
    int nblocks = (NU + upb - 1) / upb;   // 2048 for N=16M
    pos_loss_kernel<<<nblocks, BLOCK, 0, stream>>>(logits, labels, batch, partials, n);
    finalize_kernel<<<1, 256, 0, stream>>>(partials, nblocks, out);
}

// Round 9
// 47.539 us; speedup vs baseline: 4.3035x; 1.0120x over previous
//
#include <hip/hip_runtime.h>
#include <math.h>

#define POS_WEIGHT 7.0f
#define POSITION_WEIGHT 0.1f
#define BLOCK 256
#define GPT 8                  // groups per thread (group = 4 consecutive rows)

// p = sigmoid(d), stable, fast hw ops only
__device__ __forceinline__ float sigp(float d) {
    float e  = __expf(-fabsf(d));
    float rt = __builtin_amdgcn_rcpf(1.0f + e);
    return (d >= 0.0f ? 1.0f : e) * rt;
}

// weighted NLL from p: nll = -log(label ? p : 1-p), w = label ? 7 : 1
__device__ __forceinline__ void acc_nll(int la, float p, float& s_wnll, float& s_w) {
    float sel = la ? p : 1.0f - p;
    float w   = la ? POS_WEIGHT : 1.0f;
    s_wnll = fmaf(w, -__logf(sel), s_wnll);
    s_w += w;
}

__device__ __forceinline__ void pair_term(int la0, int ba0, float p0,
                                          int la1, int ba1, float p1, float& s_pos) {
    if (ba0 == ba1 && (la0 | la1)) s_pos += fabsf(p1 - p0);
}

__global__ __launch_bounds__(BLOCK, 4) void pos_loss_kernel(
    const float* __restrict__ logits,   // [n,2]
    const int*   __restrict__ labels,   // [n]
    const int*   __restrict__ batch,    // [n]
    float4* __restrict__ partials,      // [nblocks]
    int n)
{
    const int t    = threadIdx.x;
    const int lane = t & 63;
    const int NG   = n >> 2;                     // groups of 4 rows
    const int gpb  = BLOCK * GPT;                // groups per block
    const int g0   = blockIdx.x * gpb;

    float s_wnll = 0.f, s_w = 0.f, s_pos = 0.f;

    const float4* lg4 = (const float4*)logits;
    const int4*   lb4 = (const int4*)labels;
    const int4*   bt4 = (const int4*)batch;

    #pragma unroll 4
    for (int it = 0; it < GPT; ++it) {
        const int g = g0 + it * BLOCK + t;       // lane-contiguous groups
        float p0 = 0.f, p1 = 0.f, p2 = 0.f, p3 = 0.f;
        int4 la = make_int4(0, 0, 0, 0), ba = make_int4(-3, -3, -3, -3);

        if (g < NG) {
            float4 A = lg4[2 * g];               // rows 4g, 4g+1
            float4 B = lg4[2 * g + 1];           // rows 4g+2, 4g+3
            la = lb4[g];
            ba = bt4[g];
            p0 = sigp(A.y - A.x);
            p1 = sigp(A.w - A.z);
            p2 = sigp(B.y - B.x);
            p3 = sigp(B.w - B.z);
            acc_nll(la.x, p0, s_wnll, s_w);
            acc_nll(la.y, p1, s_wnll, s_w);
            acc_nll(la.z, p2, s_wnll, s_w);
            acc_nll(la.w, p3, s_wnll, s_w);
            pair_term(la.x, ba.x, p0, la.y, ba.y, p1, s_pos);
            pair_term(la.y, ba.y, p1, la.z, ba.z, p2, s_pos);
            pair_term(la.z, ba.z, p2, la.w, ba.w, p3, s_pos);
        }

        // cross-group pair (rows 4g+3, 4g+4): next lane's group head
        float np = __shfl_down(p0, 1);
        int   nla = __shfl_down(la.x, 1);
        int   nba = __shfl_down(ba.x, 1);
        if (lane == 63 && 4 * g + 4 < n) {       // wave boundary: direct fixup
            int r = 4 * g + 4;
            float2 lp = ((const float2*)logits)[r];
            np = sigp(lp.y - lp.x);
            nla = labels[r];
            nba = batch[r];
        }
        if (g < NG && 4 * g + 4 < n)
            pair_term(la.w, ba.w, p3, nla, nba, np, s_pos);
    }

    // leftover rows when n % 4 != 0 (never hit for N=16M)
    if ((n & 3) && blockIdx.x == 0 && t == 0) {
        int r0 = NG << 2;
        float pp = 0.f; int pm = -2;
        if (r0 > 0) {
            int i = r0 - 1;
            float2 lp = ((const float2*)logits)[i];
            pp = sigp(lp.y - lp.x);
            pm = (batch[i] << 1) | labels[i];
        }
        for (int r = r0; r < n; ++r) {
            float2 lp = ((const float2*)logits)[r];
            float p = sigp(lp.y - lp.x);
            int la1 = labels[r], ba1 = batch[r];
            acc_nll(la1, p, s_wnll, s_w);
            pair_term(pm & 1, pm >> 1, pp, la1, ba1, p, s_pos);
            pp = p; pm = (ba1 << 1) | la1;
        }
    }

    // wave(64) reduce -> block partial
    #pragma unroll
    for (int off = 32; off > 0; off >>= 1) {
        s_wnll += __shfl_down(s_wnll, off);
        s_w    += __shfl_down(s_w, off);
        s_pos  += __shfl_down(s_pos, off);
    }
    __shared__ float sa[BLOCK / 64], sb[BLOCK / 64], sc[BLOCK / 64];
    int wid = t >> 6;
    if (lane == 0) { sa[wid] = s_wnll; sb[wid] = s_w; sc[wid] = s_pos; }
    __syncthreads();
    if (t == 0) {
        float ta = 0.f, tb = 0.f, tc = 0.f;
        #pragma unroll
        for (int w = 0; w < BLOCK / 64; ++w) { ta += sa[w]; tb += sb[w]; tc += sc[w]; }
        partials[blockIdx.x] = make_float4(ta, tb, tc, 0.f);
    }
}

__global__ __launch_bounds__(256) void finalize_kernel(
    const float4* __restrict__ partials, int nb, float* __restrict__ out)
{
    float a = 0.f, b = 0.f, c = 0.f;
    for (int i = threadIdx.x; i < nb; i += 256) {
        float4 v = partials[i];
        a += v.x; b += v.y; c += v.z;
    }
    #pragma unroll
    for (int off = 32; off > 0; off >>= 1) {
        a += __shfl_down(a, off);
        b += __shfl_down(b, off);
        c += __shfl_down(c, off);
    }
    __shared__ float sa[4], sb[4], sc[4];
    int lane = threadIdx.x & 63, wid = threadIdx.x >> 6;
    if (lane == 0) { sa[wid] = a; sb[wid] = b; sc[wid] = c; }
    __syncthreads();
    if (threadIdx.x == 0) {
        float ta = 0.f, tb = 0.f, tc = 0.f;
        #pragma unroll
        for (int w = 0; w < 4; ++w) { ta += sa[w]; tb += sb[w]; tc += sc[w]; }
        out[0] = ta / tb + POSITION_WEIGHT * tc;
    }
}

extern "C" void kernel_launch(void* const* d_in, const int* in_sizes, int n_in,
                              void* d_out, int out_size, void* d_ws, size_t ws_size,
                              hipStream_t stream) {
    const float* logits = (const float*)d_in[0];
    const int*   labels = (const int*)d_in[1];
    const int*   batch  = (const int*)d_in[2];
    float* out = (float*)d_out;
    float4* partials = (float4*)d_ws;
    int n = in_sizes[1];   // labels element count == N

    int NG = n >> 2;
    int gpb = BLOCK * GPT;
    int nblocks = (NG + gpb - 1) / gpb;   // 2048 for N=16M
    pos_loss_kernel<<<nblocks, BLOCK, 0, stream>>>(logits, labels, batch, partials, n);
    finalize_kernel<<<1, 256, 0, stream>>>(partials, nblocks, out);
}